// Round 15
// baseline (487.264 us; speedup 1.0000x reference)
//
#include <hip/hip_runtime.h>
#include <math.h>

#define N_NODES 100000
#define N_EDGES 6400000
#define DIM     128
#define NROLES  8
#define ALPHA   0.15f
#define PR_ITERS 10

// dst buckets: 256 nodes (sort + iteration); src buckets: 512 (degree)
#define DSH      8
#define DBS      256
#define NDB      391              // ceil(100000/256)
#define SSH      9
#define SBS      512
#define NSB      196              // ceil(100000/512)
#define NBT      587              // NDB + NSB
#define NBLK_BIN 512
#define CHUNK    12500            // E / NBLK_BIN exactly
#define CAPS     18432            // sortD LDS capacity (mean 16368 + 16 sigma)
#define SPLIT    4                // threads per node in the iteration
#define ITC_BLK  1563             // ceil(N_NODES*SPLIT/256)

// ---------------------------------------------------------------------------
// K1: per-block LDS histograms: dst-buckets [0,391) + src-buckets [391,587).
// ---------------------------------------------------------------------------
__global__ __launch_bounds__(256)
void k_hist(const int* __restrict__ src, const int* __restrict__ dst,
            unsigned* __restrict__ counts) {
    __shared__ unsigned h[NBT];
    for (int i = threadIdx.x; i < NBT; i += 256) h[i] = 0;
    __syncthreads();
    int beg = blockIdx.x * CHUNK;
    int t = threadIdx.x;
    int mainEnd = beg + 12288;
    for (int e = beg + t * 4; e < mainEnd; e += 1024) {
        int4 s4 = *(const int4*)(src + e);
        int4 d4 = *(const int4*)(dst + e);
        atomicAdd(&h[((unsigned)d4.x) >> DSH], 1u);
        atomicAdd(&h[((unsigned)d4.y) >> DSH], 1u);
        atomicAdd(&h[((unsigned)d4.z) >> DSH], 1u);
        atomicAdd(&h[((unsigned)d4.w) >> DSH], 1u);
        atomicAdd(&h[NDB + (((unsigned)s4.x) >> SSH)], 1u);
        atomicAdd(&h[NDB + (((unsigned)s4.y) >> SSH)], 1u);
        atomicAdd(&h[NDB + (((unsigned)s4.z) >> SSH)], 1u);
        atomicAdd(&h[NDB + (((unsigned)s4.w) >> SSH)], 1u);
    }
    for (int e = mainEnd + t; e < beg + CHUNK; e += 256) {
        atomicAdd(&h[((unsigned)dst[e]) >> DSH], 1u);
        atomicAdd(&h[NDB + (((unsigned)src[e]) >> SSH)], 1u);
    }
    __syncthreads();
    for (int i = threadIdx.x; i < NBT; i += 256)
        counts[blockIdx.x * NBT + i] = h[i];
}

// ---------------------------------------------------------------------------
// K2a: per-bucket exclusive scan over the 512 per-block counts.
// ---------------------------------------------------------------------------
__global__ __launch_bounds__(512)
void k_scanA(const unsigned* __restrict__ counts, unsigned* __restrict__ offs,
             unsigned* __restrict__ btot) {
    int bucket = blockIdx.x, t = threadIdx.x, lane = t & 63, wv = t >> 6;
    unsigned v = counts[t * NBT + bucket], x = v;
    #pragma unroll
    for (int o = 1; o < 64; o <<= 1) {
        unsigned y = __shfl_up(x, o);
        if (lane >= o) x += y;
    }
    __shared__ unsigned wsum[8];
    if (lane == 63) wsum[wv] = x;
    __syncthreads();
    unsigned carry = 0;
    for (int w = 0; w < wv; ++w) carry += wsum[w];
    x += carry;
    offs[t * NBT + bucket] = x - v;       // exclusive
    if (t == 511) btot[bucket] = x;       // inclusive total
}

// ---------------------------------------------------------------------------
// K2b: blocks 0/1: exclusive scans of bucket totals (dst 391, src 196).
// block 2 thread 0: fp64 solve M = A^T (A A^T)^{-1}.
// ---------------------------------------------------------------------------
__global__ __launch_bounds__(512)
void k_scanB(const unsigned* __restrict__ btot, unsigned* __restrict__ bases,
             const float* __restrict__ H, float* __restrict__ Mout) {
    if (blockIdx.x == 2) {
        if (threadIdx.x != 0) return;
        double G[4][4];
        for (int i = 0; i < 4; ++i)
            for (int j = 0; j < 4; ++j) {
                double s = 0.0;
                for (int r = 0; r < NROLES; ++r)
                    s += (double)H[r * 4 + i] * (double)H[r * 4 + j];
                G[i][j] = s;
            }
        double aug[4][8];
        for (int i = 0; i < 4; ++i)
            for (int j = 0; j < 4; ++j) {
                aug[i][j] = G[i][j];
                aug[i][j + 4] = (i == j) ? 1.0 : 0.0;
            }
        for (int c = 0; c < 4; ++c) {
            int p = c; double best = fabs(aug[c][c]);
            for (int r = c + 1; r < 4; ++r) {
                double v = fabs(aug[r][c]);
                if (v > best) { best = v; p = r; }
            }
            if (p != c)
                for (int j = 0; j < 8; ++j) {
                    double tt = aug[c][j]; aug[c][j] = aug[p][j]; aug[p][j] = tt;
                }
            double piv = aug[c][c];
            for (int j = 0; j < 8; ++j) aug[c][j] /= piv;
            for (int r = 0; r < 4; ++r) {
                if (r == c) continue;
                double f = aug[r][c];
                for (int j = 0; j < 8; ++j) aug[r][j] -= f * aug[c][j];
            }
        }
        for (int r = 0; r < NROLES; ++r)
            for (int k = 0; k < 4; ++k) {
                double s = 0.0;
                for (int j = 0; j < 4; ++j)
                    s += (double)H[r * 4 + j] * aug[j][k + 4];
                Mout[r * 4 + k] = (float)s;
            }
        return;
    }
    int half = blockIdx.x;
    int len  = half ? NSB : NDB;
    int t = threadIdx.x, lane = t & 63, wv = t >> 6;
    unsigned v = (t < len) ? btot[(half ? NDB : 0) + t] : 0u, x = v;
    #pragma unroll
    for (int o = 1; o < 64; o <<= 1) {
        unsigned y = __shfl_up(x, o);
        if (lane >= o) x += y;
    }
    __shared__ unsigned wsum[8];
    if (lane == 63) wsum[wv] = x;
    __syncthreads();
    unsigned carry = 0;
    for (int w = 0; w < wv; ++w) carry += wsum[w];
    x += carry;
    if (t <= len) bases[half * 512 + t] = x - v;   // exclusive
}

// ---------------------------------------------------------------------------
// K3: placement with LDS-local counting sort + line-granular flush.
// Pass A: rec (u32, 391 dst-buckets): (dst_local(8) << 17) | src(17)
// Pass B: recs (u16, 196 src-buckets): src_local (for degree count)
// ---------------------------------------------------------------------------
__global__ __launch_bounds__(512)
void k_place(const int* __restrict__ src, const int* __restrict__ dst,
             const unsigned* __restrict__ counts, const unsigned* __restrict__ offs,
             const unsigned* __restrict__ bases,
             unsigned* __restrict__ rec, unsigned short* __restrict__ recs) {
    __shared__ unsigned buf[CHUNK];           // 50 KB; u16 overlay in pass B
    __shared__ unsigned loc[NDB + 1];
    __shared__ unsigned cur[NDB];
    __shared__ unsigned wsum[8];
    int t = threadIdx.x, lane = t & 63, wv = t >> 6;
    int blk = blockIdx.x;
    int beg = blk * CHUNK;
    int mainEnd = beg + 12288;

    // ===== pass A: dst buckets -> rec (u32) =====
    {
        unsigned c = (t < NDB) ? counts[blk * NBT + t] : 0u;
        unsigned x = c;
        #pragma unroll
        for (int o = 1; o < 64; o <<= 1) {
            unsigned y = __shfl_up(x, o);
            if (lane >= o) x += y;
        }
        if (lane == 63) wsum[wv] = x;
        __syncthreads();
        unsigned carry = 0;
        for (int w = 0; w < wv; ++w) carry += wsum[w];
        x += carry;
        if (t < NDB) { loc[t] = x - c; cur[t] = x - c; }
        if (t == NDB - 1) loc[NDB] = x;
    }
    __syncthreads();
    for (int e = beg + t * 4; e < mainEnd; e += 2048) {
        int4 s4 = *(const int4*)(src + e);
        int4 d4 = *(const int4*)(dst + e);
        #pragma unroll
        for (int k = 0; k < 4; ++k) {
            unsigned s = (unsigned)((&s4.x)[k]);
            unsigned d = (unsigned)((&d4.x)[k]);
            unsigned p = atomicAdd(&cur[d >> DSH], 1u);
            buf[p] = ((d & (DBS - 1)) << 17) | s;
        }
    }
    for (int e = mainEnd + t; e < beg + CHUNK; e += 512) {
        unsigned s = (unsigned)src[e];
        unsigned d = (unsigned)dst[e];
        unsigned p = atomicAdd(&cur[d >> DSH], 1u);
        buf[p] = ((d & (DBS - 1)) << 17) | s;
    }
    __syncthreads();
    for (int i = wv; i < NDB; i += 8) {
        unsigned lo = loc[i], n = loc[i + 1] - lo;
        unsigned gbase = bases[i] + offs[blk * NBT + i];
        for (unsigned j = lane; j < n; j += 64)
            rec[gbase + j] = buf[lo + j];
    }
    __syncthreads();

    // ===== pass B: src buckets -> recs (u16) =====
    {
        unsigned c = (t < NSB) ? counts[blk * NBT + NDB + t] : 0u;
        unsigned x = c;
        #pragma unroll
        for (int o = 1; o < 64; o <<= 1) {
            unsigned y = __shfl_up(x, o);
            if (lane >= o) x += y;
        }
        if (lane == 63) wsum[wv] = x;
        __syncthreads();
        unsigned carry = 0;
        for (int w = 0; w < wv; ++w) carry += wsum[w];
        x += carry;
        if (t < NSB) { loc[t] = x - c; cur[t] = x - c; }
        if (t == NSB - 1) loc[NSB] = x;
    }
    __syncthreads();
    unsigned short* b16 = (unsigned short*)buf;
    for (int e = beg + t * 4; e < mainEnd; e += 2048) {
        int4 s4 = *(const int4*)(src + e);
        #pragma unroll
        for (int k = 0; k < 4; ++k) {
            unsigned s = (unsigned)((&s4.x)[k]);
            unsigned p = atomicAdd(&cur[s >> SSH], 1u);
            b16[p] = (unsigned short)(s & (SBS - 1));
        }
    }
    for (int e = mainEnd + t; e < beg + CHUNK; e += 512) {
        unsigned s = (unsigned)src[e];
        unsigned p = atomicAdd(&cur[s >> SSH], 1u);
        b16[p] = (unsigned short)(s & (SBS - 1));
    }
    __syncthreads();
    for (int i = wv; i < NSB; i += 8) {
        unsigned lo = loc[i], n = loc[i + 1] - lo;
        unsigned gbase = bases[512 + i] + offs[blk * NBT + NDB + i];
        for (unsigned j = lane; j < n; j += 64)
            recs[gbase + j] = b16[lo + j];
    }
}

// ---------------------------------------------------------------------------
// K4: per-src-bucket degree count (LDS u32) + fused init of s and val0.
// ---------------------------------------------------------------------------
__global__ __launch_bounds__(256)
void k_count_init(const unsigned short* __restrict__ recs,
                  const unsigned* __restrict__ bases,
                  float* __restrict__ deg, float* __restrict__ s,
                  float* __restrict__ val0) {
    __shared__ unsigned cnt[SBS];
    int t = threadIdx.x;
    cnt[t] = 0; cnt[t + 256] = 0;
    __syncthreads();
    int b = blockIdx.x;
    unsigned st = bases[512 + b], en = bases[512 + b + 1];
    unsigned a = (st + 7u) & ~7u;
    if (a > en) a = en;
    for (unsigned i = st + t; i < a; i += 256)
        atomicAdd(&cnt[recs[i]], 1u);
    unsigned mainN = (en - a) & ~2047u;
    const uint4* rp = (const uint4*)(recs + a);
    for (unsigned i = t; i * 8u < mainN; i += 256) {
        uint4 r = rp[i];
        atomicAdd(&cnt[r.x & 0xFFFFu], 1u); atomicAdd(&cnt[r.x >> 16], 1u);
        atomicAdd(&cnt[r.y & 0xFFFFu], 1u); atomicAdd(&cnt[r.y >> 16], 1u);
        atomicAdd(&cnt[r.z & 0xFFFFu], 1u); atomicAdd(&cnt[r.z >> 16], 1u);
        atomicAdd(&cnt[r.w & 0xFFFFu], 1u); atomicAdd(&cnt[r.w >> 16], 1u);
    }
    for (unsigned i = a + mainN + t; i < en; i += 256)
        atomicAdd(&cnt[recs[i]], 1u);
    __syncthreads();
    #pragma unroll
    for (int k = 0; k < 2; ++k) {
        int v = b * SBS + t + k * 256;
        if (v < N_NODES) {
            float d = (float)cnt[t + k * 256];
            float sv = (1.0f - ALPHA) / fmaxf(d, 1.0f);
            deg[v] = d;
            s[v] = sv;
            val0[v] = sv * (1.0f / (float)N_NODES);
        }
    }
}

// ---------------------------------------------------------------------------
// K4b: per-dst-bucket sort by dst_local (8-bit LDS counting sort) + CSR row
// offsets (the sort's exclusive scan IS the row-offset table). Nodes past
// N_NODES get zero-length rows automatically. Overflow fallback scatters
// directly to global — slower but still SORTED (correctness-preserving).
// ---------------------------------------------------------------------------
__global__ __launch_bounds__(256)
void k_sortD(const unsigned* __restrict__ rec, const unsigned* __restrict__ bases,
             unsigned* __restrict__ rec2, unsigned* __restrict__ rowoff) {
    __shared__ unsigned hist[DBS];
    __shared__ unsigned wsum[4];
    __shared__ unsigned buf[CAPS];
    int t = threadIdx.x, lane = t & 63, wv = t >> 6;
    int b = blockIdx.x;
    unsigned st = bases[b], en = bases[b + 1], n = en - st;
    hist[t] = 0;
    __syncthreads();
    for (unsigned i = st + t; i < en; i += 256)
        atomicAdd(&hist[rec[i] >> 17], 1u);
    __syncthreads();
    unsigned c = hist[t], x = c;
    #pragma unroll
    for (int o = 1; o < 64; o <<= 1) {
        unsigned y = __shfl_up(x, o);
        if (lane >= o) x += y;
    }
    if (lane == 63) wsum[wv] = x;
    __syncthreads();                       // wsum ready; all hist reads done
    unsigned carry = 0;
    for (int w = 0; w < wv; ++w) carry += wsum[w];
    x += carry;
    unsigned excl = x - c;
    rowoff[b * DBS + t] = st + excl;       // CSR row offset of node b*256+t
    if (b == NDB - 1 && t == 255) rowoff[NDB * DBS] = en;   // sentinel
    hist[t] = excl;                        // cursors
    __syncthreads();
    if (n <= CAPS) {
        for (unsigned i = st + t; i < en; i += 256) {
            unsigned r = rec[i];
            unsigned p = atomicAdd(&hist[r >> 17], 1u);
            buf[p] = r;
        }
        __syncthreads();
        for (unsigned i = t; i < n; i += 256) rec2[st + i] = buf[i];
    } else {
        for (unsigned i = st + t; i < en; i += 256) {
            unsigned r = rec[i];
            rec2[st + atomicAdd(&hist[r >> 17], 1u)] = r;
        }
    }
}

// ---------------------------------------------------------------------------
// K5: one PageRank iteration, CSR row-per-thread-group. SPLIT=4 threads per
// node, each sums its quarter with 4 gathers in flight, combines via
// shfl_xor, lane q==0 writes pr/valn directly. No atomics, no LDS, no
// partials, no reduce dispatch.
// ---------------------------------------------------------------------------
__global__ __launch_bounds__(256)
void k_iterC(const unsigned* __restrict__ rec2, const unsigned* __restrict__ rowoff,
             const float* __restrict__ val, const float* __restrict__ s,
             float* __restrict__ pr, float* __restrict__ valn) {
    int g = blockIdx.x * 256 + threadIdx.x;
    int v = g >> 2, q = g & 3;
    if (v > N_NODES) return;               // rowoff[v+1] stays in-bounds
    unsigned st = rowoff[v], en = rowoff[v + 1], n = en - st;
    unsigned q0 = st + ((n * (unsigned)q) >> 2);
    unsigned q1 = st + ((n * (unsigned)(q + 1)) >> 2);
    float a0 = 0.0f, a1 = 0.0f, a2 = 0.0f, a3 = 0.0f;
    unsigned i = q0;
    for (; i + 4 <= q1; i += 4) {
        unsigned r0 = rec2[i];
        unsigned r1 = rec2[i + 1];
        unsigned r2 = rec2[i + 2];
        unsigned r3 = rec2[i + 3];
        a0 += val[r0 & 0x1FFFFu];
        a1 += val[r1 & 0x1FFFFu];
        a2 += val[r2 & 0x1FFFFu];
        a3 += val[r3 & 0x1FFFFu];
    }
    for (; i < q1; ++i) a0 += val[rec2[i] & 0x1FFFFu];
    float sum = (a0 + a1) + (a2 + a3);
    sum += __shfl_xor(sum, 1);
    sum += __shfl_xor(sum, 2);
    if (q == 0 && v < N_NODES) {
        float pv = sum + ALPHA / (float)N_NODES;
        pr[v] = pv;
        valn[v] = pv * s[v];
    }
}

// ---------------------------------------------------------------------------
// K6: fused resizer + role solve + normalize. One 64-lane wave per output row.
// ---------------------------------------------------------------------------
__global__ __launch_bounds__(256)
void k_final(const float* __restrict__ emb, const float* __restrict__ rW,
             const float* __restrict__ rb, const int* __restrict__ batch,
             const float* __restrict__ deg, const float* __restrict__ pr,
             const float* __restrict__ M, float* __restrict__ out) {
    int wid  = (blockIdx.x * blockDim.x + threadIdx.x) >> 6;
    int lane = threadIdx.x & 63;
    if (wid >= N_NODES) return;

    const float* row = emb + (size_t)wid * DIM;
    float e0 = row[lane];
    float e1 = row[lane + 64];
    float2 w0 = ((const float2*)rW)[lane];
    float2 w1 = ((const float2*)rW)[lane + 64];
    float a0 = e0 * w0.x + e1 * w1.x;
    float a1 = e0 * w0.y + e1 * w1.y;
    #pragma unroll
    for (int off = 32; off; off >>= 1) {
        a0 += __shfl_xor(a0, off);
        a1 += __shfl_xor(a1, off);
    }

    int bn = batch[wid];
    float x0 = deg[bn];
    float x1 = pr[bn];
    float x2 = a0 + rb[0];
    float x3 = a1 + rb[1];

    float wr = 0.0f;
    if (lane < NROLES) {
        const float* m = M + lane * 4;
        wr = m[0] * x0 + m[1] * x1 + m[2] * x2 + m[3] * x3;
    }
    float sq = wr * wr;
    #pragma unroll
    for (int off = 4; off; off >>= 1) sq += __shfl_xor(sq, off);
    float inv = 1.0f / fmaxf(sqrtf(sq), 1e-12f);
    if (lane < NROLES) out[(size_t)wid * NROLES + lane] = wr * inv;
}

// ---------------------------------------------------------------------------
extern "C" void kernel_launch(void* const* d_in, const int* in_sizes, int n_in,
                              void* d_out, int out_size, void* d_ws, size_t ws_size,
                              hipStream_t stream) {
    const int*   edge  = (const int*)d_in[0];
    const int*   src   = edge;
    const int*   dst   = edge + N_EDGES;
    const int*   batch = (const int*)d_in[1];
    const float* emb   = (const float*)d_in[2];
    const float* rW    = (const float*)d_in[3];
    const float* rb    = (const float*)d_in[4];
    const float* H     = (const float*)d_in[5];
    float*       out   = (float*)d_out;

    // workspace carve-up (u32 words); recs (u16) overlays rec2: recs is
    // fully consumed by k_count_init before k_sortD writes rec2.
    float*    deg    = (float*)d_ws;                 // 100352
    float*    s      = deg   + 100352;
    float*    pr     = s     + 100352;
    float*    valA   = pr    + 100352;
    float*    valB   = valA  + 100352;
    float*    M      = valB  + 100352;               // 32
    unsigned* counts = (unsigned*)(M + 32);          // 512*587
    unsigned* offs   = counts + NBLK_BIN * NBT;      // 512*587
    unsigned* btot   = offs   + NBLK_BIN * NBT;      // 1024
    unsigned* bases  = btot   + 1024;                // 1024 (dst@0, src@512)
    unsigned* rec    = bases  + 1024;                // 6.4M u32 (dst-bucketed)
    unsigned* rec2   = rec    + N_EDGES;             // 6.4M u32 (dst-sorted)
    unsigned short* recs = (unsigned short*)rec2;    // u16 overlay
    unsigned* rowoff = rec2 + N_EDGES;               // 100097 u32 (CSR)

    k_hist <<<NBLK_BIN, 256, 0, stream>>>(src, dst, counts);
    k_scanA<<<NBT,      512, 0, stream>>>(counts, offs, btot);
    k_scanB<<<3,        512, 0, stream>>>(btot, bases, H, M);
    k_place<<<NBLK_BIN, 512, 0, stream>>>(src, dst, counts, offs, bases, rec, recs);
    k_count_init<<<NSB, 256, 0, stream>>>(recs, bases, deg, s, valA);
    k_sortD<<<NDB,      256, 0, stream>>>(rec, bases, rec2, rowoff);

    float* vcur = valA;
    float* vnxt = valB;
    for (int it = 0; it < PR_ITERS; ++it) {
        k_iterC<<<ITC_BLK, 256, 0, stream>>>(rec2, rowoff, vcur, s, pr, vnxt);
        float* t = vcur; vcur = vnxt; vnxt = t;
    }

    const int FG = (N_NODES + 3) / 4;
    k_final<<<FG, 256, 0, stream>>>(emb, rW, rb, batch, deg, pr, M, out);
}

// Round 16
// 463.475 us; speedup vs baseline: 1.0513x; 1.0513x over previous
//
#include <hip/hip_runtime.h>
#include <math.h>

#define N_NODES 100000
#define N_EDGES 6400000
#define DIM     128
#define NROLES  8
#define ALPHA   0.15f
#define PR_ITERS 10

// dst buckets: 256 nodes (sort + iteration); src buckets: 512 (degree)
#define DSH      8
#define DBS      256
#define NDB      391              // ceil(100000/256)
#define SSH      9
#define SBS      512
#define NSB      196              // ceil(100000/512)
#define NBT      587              // NDB + NSB
#define NBLK_BIN 512
#define CHUNK    12500            // E / NBLK_BIN exactly
#define SEG      4                // segments per dst-bucket in the iteration
#define CAPS     17408            // sortD per-bucket capacity (mean 16368)

// ---------------------------------------------------------------------------
// K1: per-block LDS histograms: dst-buckets [0,391) + src-buckets [391,587).
// ---------------------------------------------------------------------------
__global__ __launch_bounds__(256)
void k_hist(const int* __restrict__ src, const int* __restrict__ dst,
            unsigned* __restrict__ counts) {
    __shared__ unsigned h[NBT];
    for (int i = threadIdx.x; i < NBT; i += 256) h[i] = 0;
    __syncthreads();
    int beg = blockIdx.x * CHUNK;
    int t = threadIdx.x;
    int mainEnd = beg + 12288;
    for (int e = beg + t * 4; e < mainEnd; e += 1024) {
        int4 s4 = *(const int4*)(src + e);
        int4 d4 = *(const int4*)(dst + e);
        atomicAdd(&h[((unsigned)d4.x) >> DSH], 1u);
        atomicAdd(&h[((unsigned)d4.y) >> DSH], 1u);
        atomicAdd(&h[((unsigned)d4.z) >> DSH], 1u);
        atomicAdd(&h[((unsigned)d4.w) >> DSH], 1u);
        atomicAdd(&h[NDB + (((unsigned)s4.x) >> SSH)], 1u);
        atomicAdd(&h[NDB + (((unsigned)s4.y) >> SSH)], 1u);
        atomicAdd(&h[NDB + (((unsigned)s4.z) >> SSH)], 1u);
        atomicAdd(&h[NDB + (((unsigned)s4.w) >> SSH)], 1u);
    }
    for (int e = mainEnd + t; e < beg + CHUNK; e += 256) {
        atomicAdd(&h[((unsigned)dst[e]) >> DSH], 1u);
        atomicAdd(&h[NDB + (((unsigned)src[e]) >> SSH)], 1u);
    }
    __syncthreads();
    for (int i = threadIdx.x; i < NBT; i += 256)
        counts[blockIdx.x * NBT + i] = h[i];
}

// ---------------------------------------------------------------------------
// K2a: per-bucket exclusive scan over the 512 per-block counts.
// ---------------------------------------------------------------------------
__global__ __launch_bounds__(512)
void k_scanA(const unsigned* __restrict__ counts, unsigned* __restrict__ offs,
             unsigned* __restrict__ btot) {
    int bucket = blockIdx.x, t = threadIdx.x, lane = t & 63, wv = t >> 6;
    unsigned v = counts[t * NBT + bucket], x = v;
    #pragma unroll
    for (int o = 1; o < 64; o <<= 1) {
        unsigned y = __shfl_up(x, o);
        if (lane >= o) x += y;
    }
    __shared__ unsigned wsum[8];
    if (lane == 63) wsum[wv] = x;
    __syncthreads();
    unsigned carry = 0;
    for (int w = 0; w < wv; ++w) carry += wsum[w];
    x += carry;
    offs[t * NBT + bucket] = x - v;       // exclusive
    if (t == 511) btot[bucket] = x;       // inclusive total
}

// ---------------------------------------------------------------------------
// K2b: blocks 0/1: exclusive scans of bucket totals (dst 391, src 196).
// block 2 thread 0: fp64 solve M = A^T (A A^T)^{-1}.
// ---------------------------------------------------------------------------
__global__ __launch_bounds__(512)
void k_scanB(const unsigned* __restrict__ btot, unsigned* __restrict__ bases,
             const float* __restrict__ H, float* __restrict__ Mout) {
    if (blockIdx.x == 2) {
        if (threadIdx.x != 0) return;
        double G[4][4];
        for (int i = 0; i < 4; ++i)
            for (int j = 0; j < 4; ++j) {
                double s = 0.0;
                for (int r = 0; r < NROLES; ++r)
                    s += (double)H[r * 4 + i] * (double)H[r * 4 + j];
                G[i][j] = s;
            }
        double aug[4][8];
        for (int i = 0; i < 4; ++i)
            for (int j = 0; j < 4; ++j) {
                aug[i][j] = G[i][j];
                aug[i][j + 4] = (i == j) ? 1.0 : 0.0;
            }
        for (int c = 0; c < 4; ++c) {
            int p = c; double best = fabs(aug[c][c]);
            for (int r = c + 1; r < 4; ++r) {
                double v = fabs(aug[r][c]);
                if (v > best) { best = v; p = r; }
            }
            if (p != c)
                for (int j = 0; j < 8; ++j) {
                    double tt = aug[c][j]; aug[c][j] = aug[p][j]; aug[p][j] = tt;
                }
            double piv = aug[c][c];
            for (int j = 0; j < 8; ++j) aug[c][j] /= piv;
            for (int r = 0; r < 4; ++r) {
                if (r == c) continue;
                double f = aug[r][c];
                for (int j = 0; j < 8; ++j) aug[r][j] -= f * aug[c][j];
            }
        }
        for (int r = 0; r < NROLES; ++r)
            for (int k = 0; k < 4; ++k) {
                double s = 0.0;
                for (int j = 0; j < 4; ++j)
                    s += (double)H[r * 4 + j] * aug[j][k + 4];
                Mout[r * 4 + k] = (float)s;
            }
        return;
    }
    int half = blockIdx.x;
    int len  = half ? NSB : NDB;
    int t = threadIdx.x, lane = t & 63, wv = t >> 6;
    unsigned v = (t < len) ? btot[(half ? NDB : 0) + t] : 0u, x = v;
    #pragma unroll
    for (int o = 1; o < 64; o <<= 1) {
        unsigned y = __shfl_up(x, o);
        if (lane >= o) x += y;
    }
    __shared__ unsigned wsum[8];
    if (lane == 63) wsum[wv] = x;
    __syncthreads();
    unsigned carry = 0;
    for (int w = 0; w < wv; ++w) carry += wsum[w];
    x += carry;
    if (t <= len) bases[half * 512 + t] = x - v;   // exclusive
}

// ---------------------------------------------------------------------------
// K3: placement with LDS-local counting sort + line-granular flush.
// Pass A: rec (u32, 391 dst-buckets): (dst_local(8) << 17) | src(17)
// Pass B: recs (u16, 196 src-buckets): src_local (for degree count)
// ---------------------------------------------------------------------------
__global__ __launch_bounds__(512)
void k_place(const int* __restrict__ src, const int* __restrict__ dst,
             const unsigned* __restrict__ counts, const unsigned* __restrict__ offs,
             const unsigned* __restrict__ bases,
             unsigned* __restrict__ rec, unsigned short* __restrict__ recs) {
    __shared__ unsigned buf[CHUNK];           // 50 KB; u16 overlay in pass B
    __shared__ unsigned loc[NDB + 1];
    __shared__ unsigned cur[NDB];
    __shared__ unsigned wsum[8];
    int t = threadIdx.x, lane = t & 63, wv = t >> 6;
    int blk = blockIdx.x;
    int beg = blk * CHUNK;
    int mainEnd = beg + 12288;

    // ===== pass A: dst buckets -> rec (u32) =====
    {
        unsigned c = (t < NDB) ? counts[blk * NBT + t] : 0u;
        unsigned x = c;
        #pragma unroll
        for (int o = 1; o < 64; o <<= 1) {
            unsigned y = __shfl_up(x, o);
            if (lane >= o) x += y;
        }
        if (lane == 63) wsum[wv] = x;
        __syncthreads();
        unsigned carry = 0;
        for (int w = 0; w < wv; ++w) carry += wsum[w];
        x += carry;
        if (t < NDB) { loc[t] = x - c; cur[t] = x - c; }
        if (t == NDB - 1) loc[NDB] = x;
    }
    __syncthreads();
    for (int e = beg + t * 4; e < mainEnd; e += 2048) {
        int4 s4 = *(const int4*)(src + e);
        int4 d4 = *(const int4*)(dst + e);
        #pragma unroll
        for (int k = 0; k < 4; ++k) {
            unsigned s = (unsigned)((&s4.x)[k]);
            unsigned d = (unsigned)((&d4.x)[k]);
            unsigned p = atomicAdd(&cur[d >> DSH], 1u);
            buf[p] = ((d & (DBS - 1)) << 17) | s;
        }
    }
    for (int e = mainEnd + t; e < beg + CHUNK; e += 512) {
        unsigned s = (unsigned)src[e];
        unsigned d = (unsigned)dst[e];
        unsigned p = atomicAdd(&cur[d >> DSH], 1u);
        buf[p] = ((d & (DBS - 1)) << 17) | s;
    }
    __syncthreads();
    for (int i = wv; i < NDB; i += 8) {
        unsigned lo = loc[i], n = loc[i + 1] - lo;
        unsigned gbase = bases[i] + offs[blk * NBT + i];
        for (unsigned j = lane; j < n; j += 64)
            rec[gbase + j] = buf[lo + j];
    }
    __syncthreads();

    // ===== pass B: src buckets -> recs (u16) =====
    {
        unsigned c = (t < NSB) ? counts[blk * NBT + NDB + t] : 0u;
        unsigned x = c;
        #pragma unroll
        for (int o = 1; o < 64; o <<= 1) {
            unsigned y = __shfl_up(x, o);
            if (lane >= o) x += y;
        }
        if (lane == 63) wsum[wv] = x;
        __syncthreads();
        unsigned carry = 0;
        for (int w = 0; w < wv; ++w) carry += wsum[w];
        x += carry;
        if (t < NSB) { loc[t] = x - c; cur[t] = x - c; }
        if (t == NSB - 1) loc[NSB] = x;
    }
    __syncthreads();
    unsigned short* b16 = (unsigned short*)buf;
    for (int e = beg + t * 4; e < mainEnd; e += 2048) {
        int4 s4 = *(const int4*)(src + e);
        #pragma unroll
        for (int k = 0; k < 4; ++k) {
            unsigned s = (unsigned)((&s4.x)[k]);
            unsigned p = atomicAdd(&cur[s >> SSH], 1u);
            b16[p] = (unsigned short)(s & (SBS - 1));
        }
    }
    for (int e = mainEnd + t; e < beg + CHUNK; e += 512) {
        unsigned s = (unsigned)src[e];
        unsigned p = atomicAdd(&cur[s >> SSH], 1u);
        b16[p] = (unsigned short)(s & (SBS - 1));
    }
    __syncthreads();
    for (int i = wv; i < NSB; i += 8) {
        unsigned lo = loc[i], n = loc[i + 1] - lo;
        unsigned gbase = bases[512 + i] + offs[blk * NBT + NDB + i];
        for (unsigned j = lane; j < n; j += 64)
            recs[gbase + j] = b16[lo + j];
    }
}

// ---------------------------------------------------------------------------
// K4: per-src-bucket degree count (LDS u32) + fused init of s and val0.
// ---------------------------------------------------------------------------
__global__ __launch_bounds__(256)
void k_count_init(const unsigned short* __restrict__ recs,
                  const unsigned* __restrict__ bases,
                  float* __restrict__ deg, float* __restrict__ s,
                  float* __restrict__ val0) {
    __shared__ unsigned cnt[SBS];
    int t = threadIdx.x;
    cnt[t] = 0; cnt[t + 256] = 0;
    __syncthreads();
    int b = blockIdx.x;
    unsigned st = bases[512 + b], en = bases[512 + b + 1];
    unsigned a = (st + 7u) & ~7u;
    if (a > en) a = en;
    for (unsigned i = st + t; i < a; i += 256)
        atomicAdd(&cnt[recs[i]], 1u);
    unsigned mainN = (en - a) & ~2047u;
    const uint4* rp = (const uint4*)(recs + a);
    for (unsigned i = t; i * 8u < mainN; i += 256) {
        uint4 r = rp[i];
        atomicAdd(&cnt[r.x & 0xFFFFu], 1u); atomicAdd(&cnt[r.x >> 16], 1u);
        atomicAdd(&cnt[r.y & 0xFFFFu], 1u); atomicAdd(&cnt[r.y >> 16], 1u);
        atomicAdd(&cnt[r.z & 0xFFFFu], 1u); atomicAdd(&cnt[r.z >> 16], 1u);
        atomicAdd(&cnt[r.w & 0xFFFFu], 1u); atomicAdd(&cnt[r.w >> 16], 1u);
    }
    for (unsigned i = a + mainN + t; i < en; i += 256)
        atomicAdd(&cnt[recs[i]], 1u);
    __syncthreads();
    #pragma unroll
    for (int k = 0; k < 2; ++k) {
        int v = b * SBS + t + k * 256;
        if (v < N_NODES) {
            float d = (float)cnt[t + k * 256];
            float sv = (1.0f - ALPHA) / fmaxf(d, 1.0f);
            deg[v] = d;
            s[v] = sv;
            val0[v] = sv * (1.0f / (float)N_NODES);
        }
    }
}

// ---------------------------------------------------------------------------
// K4b: per-dst-bucket sort by dst_local (8-bit LDS counting sort).
// Creates ~64-long same-dst runs for the iteration's segmented reduce.
// Fallback (n > CAPS) copies unsorted — still CORRECT, just more atomics.
// ---------------------------------------------------------------------------
__global__ __launch_bounds__(256)
void k_sortD(const unsigned* __restrict__ rec, const unsigned* __restrict__ bases,
             unsigned* __restrict__ rec2) {
    __shared__ unsigned hist[DBS];
    __shared__ unsigned wsum[4];
    __shared__ unsigned buf[CAPS];
    int t = threadIdx.x, lane = t & 63, wv = t >> 6;
    int b = blockIdx.x;
    unsigned st = bases[b], en = bases[b + 1], n = en - st;
    if (n > CAPS) {
        for (unsigned i = st + t; i < en; i += 256) rec2[i] = rec[i];
        return;
    }
    hist[t] = 0;
    __syncthreads();
    for (unsigned i = st + t; i < en; i += 256)
        atomicAdd(&hist[rec[i] >> 17], 1u);
    __syncthreads();
    unsigned c = hist[t], x = c;
    #pragma unroll
    for (int o = 1; o < 64; o <<= 1) {
        unsigned y = __shfl_up(x, o);
        if (lane >= o) x += y;
    }
    if (lane == 63) wsum[wv] = x;
    __syncthreads();                       // wsum ready; all hist reads done
    unsigned carry = 0;
    for (int w = 0; w < wv; ++w) carry += wsum[w];
    x += carry;
    hist[t] = x - c;                       // exclusive offsets -> cursors
    __syncthreads();
    for (unsigned i = st + t; i < en; i += 256) {
        unsigned r = rec[i];
        unsigned p = atomicAdd(&hist[r >> 17], 1u);
        buf[p] = r;
    }
    __syncthreads();
    for (unsigned i = t; i < n; i += 256) rec2[st + i] = buf[i];
}

// ---------------------------------------------------------------------------
// K5: PageRank accumulate on dst-sorted records with wave-segmented run
// reduction: prefix-sum + head-flag ballot; ONE LDS atomic per dst-run
// (~250K/iter instead of 6.4M).
// ---------------------------------------------------------------------------
__global__ __launch_bounds__(256)
void k_iterD(const unsigned* __restrict__ rec2, const unsigned* __restrict__ bases,
             const float* __restrict__ val, float* __restrict__ partial) {
    __shared__ float acc[DBS];
    int t = threadIdx.x, lane = t & 63;
    int b = blockIdx.x >> 2, seg = blockIdx.x & 3;
    acc[t] = 0.0f;
    __syncthreads();
    unsigned st = bases[b], en = bases[b + 1], n = en - st;
    unsigned s0 = st + (unsigned)(((unsigned long long)n * (unsigned)seg) >> 2);
    unsigned s1 = st + (unsigned)(((unsigned long long)n * (unsigned)(seg + 1)) >> 2);
    for (unsigned base = s0; base < s1; base += 256) {
        unsigned i = base + t;
        bool ok = (i < s1);
        unsigned r = ok ? rec2[i] : 0xFFFFFFFFu;
        float v = ok ? val[r & 0x1FFFFu] : 0.0f;
        unsigned k = r >> 17;              // dst_local (sentinel: 32767)
        unsigned kp = __shfl_up(k, 1);
        bool head = (lane == 0) || (kp != k);
        unsigned long long hmask = __ballot(head);
        float x = v;
        #pragma unroll
        for (int off = 1; off < 64; off <<= 1) {
            float y = __shfl_up(x, off);
            if (lane >= off) x += y;
        }
        unsigned long long le = (~0ull) >> (63 - lane);
        int H = 63 - __clzll(hmask & le);  // my run's head lane
        float prev = __shfl(x, H - 1);     // garbage when H==0 (unused)
        float runsum = x - ((H == 0) ? 0.0f : prev);
        bool tail = (lane == 63) || (((hmask >> lane) >> 1) & 1ull);
        if (tail && ok) atomicAdd(&acc[k], runsum);
    }
    __syncthreads();
    partial[((unsigned)blockIdx.x << 8) + t] = acc[t];
}

// ---------------------------------------------------------------------------
// K5b: reduce SEG=4 partials per node -> pr, valn.
// ---------------------------------------------------------------------------
__global__ __launch_bounds__(256)
void k_reduceS(const float* __restrict__ partial, const float* __restrict__ s,
               float* __restrict__ pr, float* __restrict__ valn) {
    int v = blockIdx.x * 256 + threadIdx.x;
    if (v >= N_NODES) return;
    unsigned b = (unsigned)v >> DSH;
    int local = v & (DBS - 1);
    const float* p = partial + ((b * SEG) << 8) + local;
    float sum = p[0] + p[256] + p[512] + p[768];
    float pv = sum + ALPHA / (float)N_NODES;
    pr[v] = pv;
    valn[v] = pv * s[v];
}

// ---------------------------------------------------------------------------
// K6: fused resizer + role solve + normalize. One 64-lane wave per output row.
// ---------------------------------------------------------------------------
__global__ __launch_bounds__(256)
void k_final(const float* __restrict__ emb, const float* __restrict__ rW,
             const float* __restrict__ rb, const int* __restrict__ batch,
             const float* __restrict__ deg, const float* __restrict__ pr,
             const float* __restrict__ M, float* __restrict__ out) {
    int wid  = (blockIdx.x * blockDim.x + threadIdx.x) >> 6;
    int lane = threadIdx.x & 63;
    if (wid >= N_NODES) return;

    const float* row = emb + (size_t)wid * DIM;
    float e0 = row[lane];
    float e1 = row[lane + 64];
    float2 w0 = ((const float2*)rW)[lane];
    float2 w1 = ((const float2*)rW)[lane + 64];
    float a0 = e0 * w0.x + e1 * w1.x;
    float a1 = e0 * w0.y + e1 * w1.y;
    #pragma unroll
    for (int off = 32; off; off >>= 1) {
        a0 += __shfl_xor(a0, off);
        a1 += __shfl_xor(a1, off);
    }

    int bn = batch[wid];
    float x0 = deg[bn];
    float x1 = pr[bn];
    float x2 = a0 + rb[0];
    float x3 = a1 + rb[1];

    float wr = 0.0f;
    if (lane < NROLES) {
        const float* m = M + lane * 4;
        wr = m[0] * x0 + m[1] * x1 + m[2] * x2 + m[3] * x3;
    }
    float sq = wr * wr;
    #pragma unroll
    for (int off = 4; off; off >>= 1) sq += __shfl_xor(sq, off);
    float inv = 1.0f / fmaxf(sqrtf(sq), 1e-12f);
    if (lane < NROLES) out[(size_t)wid * NROLES + lane] = wr * inv;
}

// ---------------------------------------------------------------------------
extern "C" void kernel_launch(void* const* d_in, const int* in_sizes, int n_in,
                              void* d_out, int out_size, void* d_ws, size_t ws_size,
                              hipStream_t stream) {
    const int*   edge  = (const int*)d_in[0];
    const int*   src   = edge;
    const int*   dst   = edge + N_EDGES;
    const int*   batch = (const int*)d_in[1];
    const float* emb   = (const float*)d_in[2];
    const float* rW    = (const float*)d_in[3];
    const float* rb    = (const float*)d_in[4];
    const float* H     = (const float*)d_in[5];
    float*       out   = (float*)d_out;

    // workspace carve-up (u32 words); recs (u16) overlays rec2: recs is
    // fully consumed by k_count_init before k_sortD writes rec2.
    float*    deg    = (float*)d_ws;                 // 100352
    float*    s      = deg   + 100352;
    float*    pr     = s     + 100352;
    float*    valA   = pr    + 100352;
    float*    valB   = valA  + 100352;
    float*    M      = valB  + 100352;               // 32
    unsigned* counts = (unsigned*)(M + 32);          // 512*587
    unsigned* offs   = counts + NBLK_BIN * NBT;      // 512*587
    unsigned* btot   = offs   + NBLK_BIN * NBT;      // 1024
    unsigned* bases  = btot   + 1024;                // 1024 (dst@0, src@512)
    unsigned* rec    = bases  + 1024;                // 6.4M u32 (dst-bucketed)
    unsigned* rec2   = rec    + N_EDGES;             // 6.4M u32 (dst-sorted)
    unsigned short* recs = (unsigned short*)rec2;    // u16 overlay
    float*    partial = (float*)(rec2 + N_EDGES);    // 1564*256 f32

    k_hist <<<NBLK_BIN, 256, 0, stream>>>(src, dst, counts);
    k_scanA<<<NBT,      512, 0, stream>>>(counts, offs, btot);
    k_scanB<<<3,        512, 0, stream>>>(btot, bases, H, M);
    k_place<<<NBLK_BIN, 512, 0, stream>>>(src, dst, counts, offs, bases, rec, recs);
    k_count_init<<<NSB, 256, 0, stream>>>(recs, bases, deg, s, valA);
    k_sortD<<<NDB,      256, 0, stream>>>(rec, bases, rec2);

    float* vcur = valA;
    float* vnxt = valB;
    for (int it = 0; it < PR_ITERS; ++it) {
        k_iterD <<<NDB * SEG, 256, 0, stream>>>(rec2, bases, vcur, partial);
        k_reduceS<<<NDB, 256, 0, stream>>>(partial, s, pr, vnxt);
        float* t = vcur; vcur = vnxt; vnxt = t;
    }

    const int FG = (N_NODES + 3) / 4;
    k_final<<<FG, 256, 0, stream>>>(emb, rW, rb, batch, deg, pr, M, out);
}